// Round 8
// baseline (203.410 us; speedup 1.0000x reference)
//
#include <hip/hip_runtime.h>
#include <hip/hip_bf16.h>
#include <hip/hip_fp16.h>

#define F 128
#define HID 64
#define KMAX 4
#define DEG_CAP 256   // KMAX * 64
#define NT 32         // nodes per block in dense kernels
#define REP 8         // histogram replicas

// ---------------------------------------------------------------------------
// hist_quad: 4 edges per thread, intra-quad dedup -> <=4 independent
// returning atomics in flight per thread. No LDS, small VGPR -> high occ.
// ---------------------------------------------------------------------------
__global__ __launch_bounds__(256) void hist_quad(
    const int* __restrict__ dst, int* cnt, int* __restrict__ rank,
    int e, int n)
{
    int t = blockIdx.x * 256 + threadIdx.x;
    int i0 = t * 4;
    if (i0 >= e) return;
    int rep = blockIdx.x & (REP - 1);

    int d[4], base[4], first[4], before[4];
    if (i0 + 3 < e) {
        int4 dv = *(const int4*)&dst[i0];
        d[0] = dv.x; d[1] = dv.y; d[2] = dv.z; d[3] = dv.w;
        #pragma unroll
        for (int j = 0; j < 4; ++j) {
            int bf = 0, fs = j, tot = 0;
            #pragma unroll
            for (int k = 0; k < 4; ++k) {
                bool eq = (d[k] == d[j]);
                if (eq && k < j) ++bf;
                if (eq && k < fs) fs = k;
                if (eq) ++tot;
            }
            first[j] = fs; before[j] = bf;
            if (fs == j) base[j] = atomicAdd(&cnt[rep * n + d[j]], tot);
        }
        int4 rv;
        rv.x = base[first[0]] + before[0];
        rv.y = base[first[1]] + before[1];
        rv.z = base[first[2]] + before[2];
        rv.w = base[first[3]] + before[3];
        *(int4*)&rank[i0] = rv;
    } else {
        for (int j = 0; i0 + j < e; ++j) {
            int dj = dst[i0 + j];
            rank[i0 + j] = atomicAdd(&cnt[rep * n + dj], 1);
        }
    }
}

// ---------------------------------------------------------------------------
// scan_block: replica fold (repoff) + per-block exclusive scan of totals.
// rstart stays PARTIAL; consumers add the top-level offset from bsum inline.
// ---------------------------------------------------------------------------
__global__ __launch_bounds__(256) void scan_block(
    const int* __restrict__ cnt, int* __restrict__ repoff,
    int* __restrict__ rstart, int* __restrict__ bsum, int n)
{
    int tid = threadIdx.x;
    int i = blockIdx.x * 256 + tid;
    int v = 0;
    if (i < n) {
        int run = 0;
        #pragma unroll
        for (int r = 0; r < REP; ++r) {
            int c = cnt[r * n + i];
            repoff[r * n + i] = run;
            run += c;
        }
        v = run;
    }
    int lane = tid & 63, wv = tid >> 6;
    int x = v;
    #pragma unroll
    for (int off = 1; off < 64; off <<= 1) {
        int t = __shfl_up(x, off, 64);
        if (lane >= off) x += t;
    }
    __shared__ int wsum[4];
    if (lane == 63) wsum[wv] = x;
    __syncthreads();
    int woff = 0;
    #pragma unroll
    for (int wdx = 0; wdx < 4; ++wdx) woff += (wdx < wv) ? wsum[wdx] : 0;
    int incl = x + woff;
    if (i < n) rstart[i] = incl - v;
    if (tid == 255) bsum[blockIdx.x] = incl;
}

// ---------------------------------------------------------------------------
// fill_quad: atomic-free scatter, 4 edges/thread (int4 loads, 4 stores).
// pos = rstart_partial[d] + boff[d>>8] + repoff[rep][d] + rank[i]
// ---------------------------------------------------------------------------
__global__ __launch_bounds__(256) void fill_quad(
    const int* __restrict__ dst, const int* __restrict__ src,
    const int* __restrict__ rank, const int* __restrict__ rstart,
    const int* __restrict__ repoff, const int* __restrict__ bsum,
    int* __restrict__ src_sorted, int n, int nb, int e)
{
    __shared__ int sbo[64];
    int tid = threadIdx.x;
    if (tid < 64) {
        int v = (tid < nb) ? bsum[tid] : 0;
        int x = v;
        #pragma unroll
        for (int off = 1; off < 64; off <<= 1) {
            int t = __shfl_up(x, off, 64);
            if (tid >= off) x += t;
        }
        sbo[tid] = x - v;
    }
    __syncthreads();
    int t = blockIdx.x * 256 + tid;
    int i0 = t * 4;
    if (i0 >= e) return;
    int rep = blockIdx.x & (REP - 1);

    if (i0 + 3 < e) {
        int4 dv = *(const int4*)&dst[i0];
        int4 sv = *(const int4*)&src[i0];
        int4 rv = *(const int4*)&rank[i0];
        int dd[4] = {dv.x, dv.y, dv.z, dv.w};
        int ss[4] = {sv.x, sv.y, sv.z, sv.w};
        int rr[4] = {rv.x, rv.y, rv.z, rv.w};
        #pragma unroll
        for (int j = 0; j < 4; ++j) {
            int d = dd[j];
            int pos = rstart[d] + sbo[d >> 8] + repoff[rep * n + d] + rr[j];
            src_sorted[pos] = ss[j];
        }
    } else {
        for (int j = 0; i0 + j < e; ++j) {
            int d = dst[i0 + j];
            int pos = rstart[d] + sbo[d >> 8] + repoff[rep * n + d] + rank[i0 + j];
            src_sorted[pos] = src[i0 + j];
        }
    }
}

// ---------------------------------------------------------------------------
// node_mlp_v3: register-tiled GEMM chain, 32 nodes/block. Per-block v1.
// Outputs fp16 Mh, p = M.v1, q = h.attn[F:].
// ---------------------------------------------------------------------------
__global__ __launch_bounds__(256) void node_mlp_v3(
    const float* __restrict__ h,
    const float* __restrict__ W1, const float* __restrict__ b1,
    const float* __restrict__ W2, const float* __restrict__ b2,
    const float* __restrict__ nk, const float* __restrict__ attn,
    __half* __restrict__ Mh, float* __restrict__ p, float* __restrict__ q,
    int n)
{
    __shared__ __align__(16) float hsTs[NT][F];   // h, then relu(h@W1+b1)
    __shared__ __align__(16) float Wc[32][F];
    __shared__ __align__(16) float v1s[F];
    int tid = threadIdx.x;
    int bm = blockIdx.x;
    int row0 = bm * NT;
    int j0 = (tid & 31) * 4;
    int r0 = (tid >> 5) * 4;

    #pragma unroll
    for (int it = 0; it < 4; ++it) {
        int s4 = tid + it * 256;
        int r = s4 >> 5, c4 = s4 & 31;
        int row = row0 + r;
        float4 v = make_float4(0, 0, 0, 0);
        if (row < n) v = *(const float4*)&h[(size_t)row * F + c4 * 4];
        *(float4*)&hsTs[r][c4 * 4] = v;
    }
    if (tid < F) {
        float a = 0.f;
        const float4* nkr = (const float4*)&nk[(size_t)tid * F];
        const float4* at4 = (const float4*)attn;
        #pragma unroll 8
        for (int j = 0; j < 32; ++j) {
            float4 nv = nkr[j]; float4 av = at4[j];
            a = fmaf(nv.x, av.x, a); a = fmaf(nv.y, av.y, a);
            a = fmaf(nv.z, av.z, a); a = fmaf(nv.w, av.w, a);
        }
        v1s[tid] = a;
    }
    __syncthreads();

    {
        int r = tid >> 3, kp = tid & 7;
        float qa = 0.f;
        #pragma unroll
        for (int c = 0; c < 4; ++c) {
            float4 hv = *(const float4*)&hsTs[r][kp * 16 + c * 4];
            float4 av = *(const float4*)&attn[F + kp * 16 + c * 4];
            qa = fmaf(hv.x, av.x, qa); qa = fmaf(hv.y, av.y, qa);
            qa = fmaf(hv.z, av.z, qa); qa = fmaf(hv.w, av.w, qa);
        }
        #pragma unroll
        for (int off = 1; off < 8; off <<= 1) qa += __shfl_xor(qa, off, 64);
        int row = row0 + r;
        if (kp == 0 && row < n) q[row] = qa;
    }

    float4 acc[4];
    {
        float4 bv = *(const float4*)&b1[j0];
        #pragma unroll
        for (int i = 0; i < 4; ++i) acc[i] = bv;
    }
    for (int cc = 0; cc < 4; ++cc) {
        int kc = ((cc + bm) & 3) * 32;
        __syncthreads();
        #pragma unroll
        for (int it = 0; it < 4; ++it) {
            int s4 = tid + it * 256;
            int wr = s4 >> 5, wc4 = s4 & 31;
            *(float4*)&Wc[wr][wc4 * 4] =
                *(const float4*)&W1[(size_t)(kc + wr) * F + wc4 * 4];
        }
        __syncthreads();
        #pragma unroll
        for (int k4 = 0; k4 < 8; ++k4) {
            int kk = k4 * 4;
            float4 a0 = *(const float4*)&hsTs[r0 + 0][kc + kk];
            float4 a1 = *(const float4*)&hsTs[r0 + 1][kc + kk];
            float4 a2 = *(const float4*)&hsTs[r0 + 2][kc + kk];
            float4 a3 = *(const float4*)&hsTs[r0 + 3][kc + kk];
            #pragma unroll
            for (int k = 0; k < 4; ++k) {
                float4 b = *(const float4*)&Wc[kk + k][j0];
                float av0 = k == 0 ? a0.x : k == 1 ? a0.y : k == 2 ? a0.z : a0.w;
                float av1 = k == 0 ? a1.x : k == 1 ? a1.y : k == 2 ? a1.z : a1.w;
                float av2 = k == 0 ? a2.x : k == 1 ? a2.y : k == 2 ? a2.z : a2.w;
                float av3 = k == 0 ? a3.x : k == 1 ? a3.y : k == 2 ? a3.z : a3.w;
                acc[0].x = fmaf(av0, b.x, acc[0].x); acc[0].y = fmaf(av0, b.y, acc[0].y);
                acc[0].z = fmaf(av0, b.z, acc[0].z); acc[0].w = fmaf(av0, b.w, acc[0].w);
                acc[1].x = fmaf(av1, b.x, acc[1].x); acc[1].y = fmaf(av1, b.y, acc[1].y);
                acc[1].z = fmaf(av1, b.z, acc[1].z); acc[1].w = fmaf(av1, b.w, acc[1].w);
                acc[2].x = fmaf(av2, b.x, acc[2].x); acc[2].y = fmaf(av2, b.y, acc[2].y);
                acc[2].z = fmaf(av2, b.z, acc[2].z); acc[2].w = fmaf(av2, b.w, acc[2].w);
                acc[3].x = fmaf(av3, b.x, acc[3].x); acc[3].y = fmaf(av3, b.y, acc[3].y);
                acc[3].z = fmaf(av3, b.z, acc[3].z); acc[3].w = fmaf(av3, b.w, acc[3].w);
            }
        }
    }
    __syncthreads();
    #pragma unroll
    for (int i = 0; i < 4; ++i) {
        float4 t = acc[i];
        t.x = fmaxf(t.x, 0.f); t.y = fmaxf(t.y, 0.f);
        t.z = fmaxf(t.z, 0.f); t.w = fmaxf(t.w, 0.f);
        *(float4*)&hsTs[r0 + i][j0] = t;
    }

    {
        float4 bv = *(const float4*)&b2[j0];
        #pragma unroll
        for (int i = 0; i < 4; ++i) acc[i] = bv;
    }
    for (int cc = 0; cc < 4; ++cc) {
        int kc = ((cc + bm) & 3) * 32;
        __syncthreads();
        #pragma unroll
        for (int it = 0; it < 4; ++it) {
            int s4 = tid + it * 256;
            int wr = s4 >> 5, wc4 = s4 & 31;
            *(float4*)&Wc[wr][wc4 * 4] =
                *(const float4*)&W2[(size_t)(kc + wr) * F + wc4 * 4];
        }
        __syncthreads();
        #pragma unroll
        for (int k4 = 0; k4 < 8; ++k4) {
            int kk = k4 * 4;
            float4 a0 = *(const float4*)&hsTs[r0 + 0][kc + kk];
            float4 a1 = *(const float4*)&hsTs[r0 + 1][kc + kk];
            float4 a2 = *(const float4*)&hsTs[r0 + 2][kc + kk];
            float4 a3 = *(const float4*)&hsTs[r0 + 3][kc + kk];
            #pragma unroll
            for (int k = 0; k < 4; ++k) {
                float4 b = *(const float4*)&Wc[kk + k][j0];
                float av0 = k == 0 ? a0.x : k == 1 ? a0.y : k == 2 ? a0.z : a0.w;
                float av1 = k == 0 ? a1.x : k == 1 ? a1.y : k == 2 ? a1.z : a1.w;
                float av2 = k == 0 ? a2.x : k == 1 ? a2.y : k == 2 ? a2.z : a2.w;
                float av3 = k == 0 ? a3.x : k == 1 ? a3.y : k == 2 ? a3.z : a3.w;
                acc[0].x = fmaf(av0, b.x, acc[0].x); acc[0].y = fmaf(av0, b.y, acc[0].y);
                acc[0].z = fmaf(av0, b.z, acc[0].z); acc[0].w = fmaf(av0, b.w, acc[0].w);
                acc[1].x = fmaf(av1, b.x, acc[1].x); acc[1].y = fmaf(av1, b.y, acc[1].y);
                acc[1].z = fmaf(av1, b.z, acc[1].z); acc[1].w = fmaf(av1, b.w, acc[1].w);
                acc[2].x = fmaf(av2, b.x, acc[2].x); acc[2].y = fmaf(av2, b.y, acc[2].y);
                acc[2].z = fmaf(av2, b.z, acc[2].z); acc[2].w = fmaf(av2, b.w, acc[2].w);
                acc[3].x = fmaf(av3, b.x, acc[3].x); acc[3].y = fmaf(av3, b.y, acc[3].y);
                acc[3].z = fmaf(av3, b.z, acc[3].z); acc[3].w = fmaf(av3, b.w, acc[3].w);
            }
        }
    }

    float4 v1v = *(const float4*)&v1s[j0];
    #pragma unroll
    for (int i = 0; i < 4; ++i) {
        int row = row0 + r0 + i;
        if (row < n) {
            __half hv[4];
            hv[0] = __float2half(acc[i].x); hv[1] = __float2half(acc[i].y);
            hv[2] = __float2half(acc[i].z); hv[3] = __float2half(acc[i].w);
            *(uint2*)&Mh[(size_t)row * F + j0] = *(uint2*)hv;
        }
        float pp = acc[i].x * v1v.x + acc[i].y * v1v.y +
                   acc[i].z * v1v.z + acc[i].w * v1v.w;
        #pragma unroll
        for (int off = 1; off < 32; off <<= 1) pp += __shfl_xor(pp, off, 64);
        if ((tid & 31) == 0 && row < n) p[row] = pp;
    }
}

// ---------------------------------------------------------------------------
// One WAVE per destination node: segment softmax + weighted fp16 gather.
// Quarter-wave (16 lanes x 16B) covers one 256B Mh row -> 4 edges per load
// instruction, 4 loads per lane in flight per batch of 16 edges.
// ---------------------------------------------------------------------------
__global__ __launch_bounds__(256) void agg_softmax_gather(
    const __half* __restrict__ Mh, const float* __restrict__ p,
    const float* __restrict__ q, const int* __restrict__ rstart,
    const int* __restrict__ bsum, const int* __restrict__ src_sorted,
    float* __restrict__ agg, int n, int nb, int e)
{
    __shared__ int2 buf[4][DEG_CAP];
    __shared__ int sbo[64];
    int tid = threadIdx.x;
    if (tid < 64) {
        int v = (tid < nb) ? bsum[tid] : 0;
        int x = v;
        #pragma unroll
        for (int off = 1; off < 64; off <<= 1) {
            int t = __shfl_up(x, off, 64);
            if (tid >= off) x += t;
        }
        sbo[tid] = x - v;
    }
    __syncthreads();

    int lane = tid & 63;
    int wv   = tid >> 6;
    int node = blockIdx.x * 4 + wv;
    if (node >= n) return;

    int start = rstart[node] + sbo[node >> 8];
    int end   = (node + 1 < n) ? rstart[node + 1] + sbo[(node + 1) >> 8] : e;
    int deg   = end - start;
    float qn  = q[node];

    float w[KMAX];
    int   sidx[KMAX];
    float lmax = -1e30f;

    #pragma unroll
    for (int k = 0; k < KMAX; ++k) {
        int i = start + lane + (k << 6);
        bool valid = (i < end);
        int sv = valid ? src_sorted[i] : 0;
        float pv = valid ? p[sv] : 0.0f;
        float sc = pv + qn;
        float ev = (sc > 0.0f) ? sc : 0.2f * sc;
        w[k] = valid ? ev : -1e30f;
        sidx[k] = sv;
        lmax = fmaxf(lmax, w[k]);
    }
    for (int i = start + DEG_CAP + lane; i < end; i += 64) {
        float sc = p[src_sorted[i]] + qn;
        float ev = (sc > 0.0f) ? sc : 0.2f * sc;
        lmax = fmaxf(lmax, ev);
    }
    #pragma unroll
    for (int off = 32; off >= 1; off >>= 1)
        lmax = fmaxf(lmax, __shfl_xor(lmax, off, 64));

    float lsum = 0.0f;
    #pragma unroll
    for (int k = 0; k < KMAX; ++k) {
        float ex = (w[k] > -1e29f) ? __expf(w[k] - lmax) : 0.0f;
        w[k] = ex;
        lsum += ex;
    }
    for (int i = start + DEG_CAP + lane; i < end; i += 64) {
        float sc = p[src_sorted[i]] + qn;
        float ev = (sc > 0.0f) ? sc : 0.2f * sc;
        lsum += __expf(ev - lmax);
    }
    #pragma unroll
    for (int off = 32; off >= 1; off >>= 1)
        lsum += __shfl_xor(lsum, off, 64);
    float inv = 1.0f / (lsum + 1e-9f);

    #pragma unroll
    for (int k = 0; k < KMAX; ++k)
        buf[wv][lane + (k << 6)] = make_int2(__float_as_int(w[k] * inv), sidx[k]);

    const uint4* M16 = (const uint4*)Mh;   // 16B = 8 halfs; row = 16 uint4
    int sub16 = lane & 15;
    int quar  = lane >> 4;
    float acc[8] = {0.f, 0.f, 0.f, 0.f, 0.f, 0.f, 0.f, 0.f};
    int lim = min(deg, DEG_CAP);
    lim = (lim + 15) & ~15;              // padded slots carry weight 0

    for (int base = 0; base < lim; base += 16) {
        int2  rr[4];
        uint4 mm[4];
        #pragma unroll
        for (int u = 0; u < 4; ++u) rr[u] = buf[wv][base + quar + 4 * u];
        #pragma unroll
        for (int u = 0; u < 4; ++u) mm[u] = M16[(size_t)rr[u].y * 16 + sub16];
        #pragma unroll
        for (int u = 0; u < 4; ++u) {
            float wu = __int_as_float(rr[u].x);
            const __half2* hp = (const __half2*)&mm[u];
            float2 f0 = __half22float2(hp[0]);
            float2 f1 = __half22float2(hp[1]);
            float2 f2 = __half22float2(hp[2]);
            float2 f3 = __half22float2(hp[3]);
            acc[0] = fmaf(wu, f0.x, acc[0]); acc[1] = fmaf(wu, f0.y, acc[1]);
            acc[2] = fmaf(wu, f1.x, acc[2]); acc[3] = fmaf(wu, f1.y, acc[3]);
            acc[4] = fmaf(wu, f2.x, acc[4]); acc[5] = fmaf(wu, f2.y, acc[5]);
            acc[6] = fmaf(wu, f3.x, acc[6]); acc[7] = fmaf(wu, f3.y, acc[7]);
        }
    }

    for (int base = start + DEG_CAP; base < end; base += 64) {  // deg>256 only
        int i = base + lane;
        float ex = 0.f; int sv = 0;
        if (i < end) {
            sv = src_sorted[i];
            float sc = p[sv] + qn;
            float ev = (sc > 0.0f) ? sc : 0.2f * sc;
            ex = __expf(ev - lmax) * inv;
        }
        buf[wv][lane] = make_int2(__float_as_int(ex), sv);
        for (int b2 = 0; b2 < 64; b2 += 4) {
            int2 rr = buf[wv][b2 + quar];
            uint4 mm = M16[(size_t)rr.y * 16 + sub16];
            float wu = __int_as_float(rr.x);
            const __half2* hp = (const __half2*)&mm;
            float2 f0 = __half22float2(hp[0]);
            float2 f1 = __half22float2(hp[1]);
            float2 f2 = __half22float2(hp[2]);
            float2 f3 = __half22float2(hp[3]);
            acc[0] = fmaf(wu, f0.x, acc[0]); acc[1] = fmaf(wu, f0.y, acc[1]);
            acc[2] = fmaf(wu, f1.x, acc[2]); acc[3] = fmaf(wu, f1.y, acc[3]);
            acc[4] = fmaf(wu, f2.x, acc[4]); acc[5] = fmaf(wu, f2.y, acc[5]);
            acc[6] = fmaf(wu, f3.x, acc[6]); acc[7] = fmaf(wu, f3.y, acc[7]);
        }
    }

    #pragma unroll
    for (int j = 0; j < 8; ++j) {
        acc[j] += __shfl_xor(acc[j], 16, 64);
        acc[j] += __shfl_xor(acc[j], 32, 64);
    }
    if (quar == 0) {
        float* dst0 = &agg[(size_t)node * F + sub16 * 8];
        *(float4*)dst0       = make_float4(acc[0], acc[1], acc[2], acc[3]);
        *(float4*)(dst0 + 4) = make_float4(acc[4], acc[5], acc[6], acc[7]);
    }
}

// ---------------------------------------------------------------------------
// update_readout_v2: register-tiled. 32 nodes/block.
// ---------------------------------------------------------------------------
__global__ __launch_bounds__(256) void update_readout_v2(
    const float* __restrict__ agg, const float* __restrict__ h,
    const float* __restrict__ Wu, const float* __restrict__ bu,
    const float* __restrict__ Wr1, const float* __restrict__ br1,
    const float* __restrict__ Wr2, const float* __restrict__ br2,
    float* __restrict__ out, int n)
{
    __shared__ __align__(16) float X[NT][2 * F];
    __shared__ __align__(16) float hn[NT][F];
    __shared__ __align__(16) float Wc[32][F];
    int tid = threadIdx.x;
    int row0 = blockIdx.x * NT;
    int j0 = (tid & 31) * 4;
    int r0 = (tid >> 5) * 4;

    #pragma unroll
    for (int it = 0; it < 8; ++it) {
        int s4 = tid + it * 256;
        int r = s4 >> 6, c4 = s4 & 63;
        int row = row0 + r;
        float4 v = make_float4(0, 0, 0, 0);
        if (row < n) {
            if (c4 < 32) v = *(const float4*)&agg[(size_t)row * F + c4 * 4];
            else         v = *(const float4*)&h[(size_t)row * F + (c4 - 32) * 4];
        }
        *(float4*)&X[r][c4 * 4] = v;
    }

    float4 acc[4];
    {
        float4 bv = *(const float4*)&bu[j0];
        #pragma unroll
        for (int i = 0; i < 4; ++i) acc[i] = bv;
    }
    for (int cc = 0; cc < 8; ++cc) {
        int kc = ((cc + (int)blockIdx.x) & 7) * 32;
        __syncthreads();
        #pragma unroll
        for (int it = 0; it < 4; ++it) {
            int s4 = tid + it * 256;
            int wr = s4 >> 5, wc4 = s4 & 31;
            *(float4*)&Wc[wr][wc4 * 4] =
                *(const float4*)&Wu[(size_t)(kc + wr) * F + wc4 * 4];
        }
        __syncthreads();
        #pragma unroll
        for (int k4 = 0; k4 < 8; ++k4) {
            int kk = k4 * 4;
            float4 a0 = *(const float4*)&X[r0 + 0][kc + kk];
            float4 a1 = *(const float4*)&X[r0 + 1][kc + kk];
            float4 a2 = *(const float4*)&X[r0 + 2][kc + kk];
            float4 a3 = *(const float4*)&X[r0 + 3][kc + kk];
            #pragma unroll
            for (int k = 0; k < 4; ++k) {
                float4 b = *(const float4*)&Wc[kk + k][j0];
                float av0 = k == 0 ? a0.x : k == 1 ? a0.y : k == 2 ? a0.z : a0.w;
                float av1 = k == 0 ? a1.x : k == 1 ? a1.y : k == 2 ? a1.z : a1.w;
                float av2 = k == 0 ? a2.x : k == 1 ? a2.y : k == 2 ? a2.z : a2.w;
                float av3 = k == 0 ? a3.x : k == 1 ? a3.y : k == 2 ? a3.z : a3.w;
                acc[0].x = fmaf(av0, b.x, acc[0].x); acc[0].y = fmaf(av0, b.y, acc[0].y);
                acc[0].z = fmaf(av0, b.z, acc[0].z); acc[0].w = fmaf(av0, b.w, acc[0].w);
                acc[1].x = fmaf(av1, b.x, acc[1].x); acc[1].y = fmaf(av1, b.y, acc[1].y);
                acc[1].z = fmaf(av1, b.z, acc[1].z); acc[1].w = fmaf(av1, b.w, acc[1].w);
                acc[2].x = fmaf(av2, b.x, acc[2].x); acc[2].y = fmaf(av2, b.y, acc[2].y);
                acc[2].z = fmaf(av2, b.z, acc[2].z); acc[2].w = fmaf(av2, b.w, acc[2].w);
                acc[3].x = fmaf(av3, b.x, acc[3].x); acc[3].y = fmaf(av3, b.y, acc[3].y);
                acc[3].z = fmaf(av3, b.z, acc[3].z); acc[3].w = fmaf(av3, b.w, acc[3].w);
            }
        }
    }
    __syncthreads();
    #pragma unroll
    for (int i = 0; i < 4; ++i) {
        float4 t = acc[i];
        t.x = fmaxf(t.x, 0.f); t.y = fmaxf(t.y, 0.f);
        t.z = fmaxf(t.z, 0.f); t.w = fmaxf(t.w, 0.f);
        *(float4*)&hn[r0 + i][j0] = t;
    }

    int h0 = (tid & 31) * 2;
    float r1[4][2];
    {
        float b0 = br1[h0], b1v = br1[h0 + 1];
        #pragma unroll
        for (int i = 0; i < 4; ++i) { r1[i][0] = b0; r1[i][1] = b1v; }
    }
    float* Wcr = &Wc[0][0];
    for (int cc = 0; cc < 2; ++cc) {
        int kc = cc * 64;
        __syncthreads();
        #pragma unroll
        for (int it = 0; it < 4; ++it) {
            int s4 = tid + it * 256;
            int wr = s4 >> 4, wc4 = s4 & 15;
            *(float4*)&Wcr[wr * 64 + wc4 * 4] =
                *(const float4*)&Wr1[(size_t)(kc + wr) * HID + wc4 * 4];
        }
        __syncthreads();
        #pragma unroll
        for (int k4 = 0; k4 < 16; ++k4) {
            int kk = k4 * 4;
            float4 a0 = *(const float4*)&hn[r0 + 0][kc + kk];
            float4 a1 = *(const float4*)&hn[r0 + 1][kc + kk];
            float4 a2 = *(const float4*)&hn[r0 + 2][kc + kk];
            float4 a3 = *(const float4*)&hn[r0 + 3][kc + kk];
            #pragma unroll
            for (int k = 0; k < 4; ++k) {
                float2 b = *(const float2*)&Wcr[(kk + k) * 64 + h0];
                float av0 = k == 0 ? a0.x : k == 1 ? a0.y : k == 2 ? a0.z : a0.w;
                float av1 = k == 0 ? a1.x : k == 1 ? a1.y : k == 2 ? a1.z : a1.w;
                float av2 = k == 0 ? a2.x : k == 1 ? a2.y : k == 2 ? a2.z : a2.w;
                float av3 = k == 0 ? a3.x : k == 1 ? a3.y : k == 2 ? a3.z : a3.w;
                r1[0][0] = fmaf(av0, b.x, r1[0][0]); r1[0][1] = fmaf(av0, b.y, r1[0][1]);
                r1[1][0] = fmaf(av1, b.x, r1[1][0]); r1[1][1] = fmaf(av1, b.y, r1[1][1]);
                r1[2][0] = fmaf(av2, b.x, r1[2][0]); r1[2][1] = fmaf(av2, b.y, r1[2][1]);
                r1[3][0] = fmaf(av3, b.x, r1[3][0]); r1[3][1] = fmaf(av3, b.y, r1[3][1]);
            }
        }
    }

    float wa = Wr2[h0], wb = Wr2[h0 + 1];
    float b2v = br2[0];
    #pragma unroll
    for (int i = 0; i < 4; ++i) {
        float s = fmaxf(r1[i][0], 0.f) * wa + fmaxf(r1[i][1], 0.f) * wb;
        #pragma unroll
        for (int off = 1; off < 32; off <<= 1) s += __shfl_xor(s, off, 64);
        int row = row0 + r0 + i;
        if ((tid & 31) == 0 && row < n) out[row] = s + b2v;
    }
}

// ---------------------------------------------------------------------------
extern "C" void kernel_launch(void* const* d_in, const int* in_sizes, int n_in,
                              void* d_out, int out_size, void* d_ws, size_t ws_size,
                              hipStream_t stream) {
    const float* h    = (const float*)d_in[0];
    const int*   src  = (const int*)d_in[1];
    const int*   dst  = (const int*)d_in[2];
    const float* W1   = (const float*)d_in[3];
    const float* b1   = (const float*)d_in[4];
    const float* W2   = (const float*)d_in[5];
    const float* b2   = (const float*)d_in[6];
    const float* nk   = (const float*)d_in[7];
    const float* attn = (const float*)d_in[8];
    const float* Wu   = (const float*)d_in[9];
    const float* bu   = (const float*)d_in[10];
    const float* Wr1  = (const float*)d_in[11];
    const float* br1  = (const float*)d_in[12];
    const float* Wr2  = (const float*)d_in[13];
    const float* br2  = (const float*)d_in[14];
    float* out = (float*)d_out;

    int n = in_sizes[0] / F;    // 10000
    int e = in_sizes[1];        // 640000
    int nb = (n + 255) / 256;   // 40
    int quadBlocks = ((e + 3) / 4 + 255) / 256;   // 625
    int mlpBlocks  = (n + NT - 1) / NT;           // 313

    char* ws = (char*)d_ws;
    size_t off = 0;
    auto alloc = [&](size_t bytes) {
        void* pp = ws + off;
        off += (bytes + 511) & ~(size_t)511;
        return pp;
    };
    __half* Mh     = (__half*)alloc((size_t)n * F * 2);
    float* aggws   = (float*)alloc((size_t)n * F * 4);
    float* p       = (float*)alloc((size_t)n * 4);
    float* q       = (float*)alloc((size_t)n * 4);
    int*   cnt     = (int*)alloc((size_t)REP * n * 4);
    int*   repoff  = (int*)alloc((size_t)REP * n * 4);
    int*   rstart  = (int*)alloc((size_t)(n + 1) * 4);
    int*   bsum    = (int*)alloc((size_t)(nb + 1) * 4);
    int*   rank    = (int*)alloc((size_t)e * 4);
    int*   srcsort = (int*)alloc((size_t)e * 4);

    hipMemsetAsync(cnt, 0, (size_t)REP * n * 4, stream);
    hist_quad<<<quadBlocks, 256, 0, stream>>>(dst, cnt, rank, e, n);
    scan_block<<<nb, 256, 0, stream>>>(cnt, repoff, rstart, bsum, n);
    fill_quad<<<quadBlocks, 256, 0, stream>>>(dst, src, rank, rstart,
                                              repoff, bsum, srcsort,
                                              n, nb, e);
    node_mlp_v3<<<mlpBlocks, 256, 0, stream>>>(h, W1, b1, W2, b2, nk, attn,
                                               Mh, p, q, n);
    agg_softmax_gather<<<(n + 3) / 4, 256, 0, stream>>>(Mh, p, q, rstart, bsum,
                                                        srcsort, aggws, n, nb, e);
    update_readout_v2<<<mlpBlocks, 256, 0, stream>>>(aggws, h, Wu, bu,
                                                     Wr1, br1, Wr2, br2,
                                                     out, n);
}